// Round 6
// baseline (270.915 us; speedup 1.0000x reference)
//
#include <hip/hip_runtime.h>

#define B_  4
#define D_  512
#define H_  8
#define DV_ 64
#define S_  2048

typedef __bf16 bf16;
typedef bf16  bf16x8 __attribute__((ext_vector_type(8)));
typedef bf16  bf16x4 __attribute__((ext_vector_type(4)));
typedef float f32x4  __attribute__((ext_vector_type(4)));

#define MFMA(a, b, c) __builtin_amdgcn_mfma_f32_16x16x32_bf16((a), (b), (c), 0, 0, 0)

// async global->LDS, 16B per lane; LDS dest must be wave-uniform base + lane*16
#define GLOAD_LDS(g, l)                                                     \
    __builtin_amdgcn_global_load_lds(                                       \
        (const __attribute__((address_space(1))) void*)(g),                 \
        (__attribute__((address_space(3))) void*)(l), 16, 0, 0)

// ---------------------------------------------------------------------------
// Kernel 1: prep = transpose x (B,D,S fp32 -> B,S,D bf16)  +  pack weights
// ---------------------------------------------------------------------------
__global__ __launch_bounds__(256) void prep(
    const float* __restrict__ x, const float* __restrict__ Wq,
    const float* __restrict__ Wk, const float* __restrict__ Wv,
    const float* __restrict__ W0, bf16* __restrict__ xb, bf16* __restrict__ Wb) {
    const int bid = blockIdx.x;
    if (bid < 4096) {                            // transpose part
        __shared__ float tile[32][33];
        const int sblk = bid % 64;               // S/32
        const int dblk = (bid / 64) % 16;        // D/32
        const int b    = bid / 1024;
        const int d0 = dblk * 32, s0 = sblk * 32;
        const int tx = threadIdx.x & 31;
        const int ty = threadIdx.x >> 5;         // 0..7
        const float* xp = x + (size_t)b * D_ * S_;
#pragma unroll
        for (int i = 0; i < 32; i += 8)
            tile[ty + i][tx] = xp[(size_t)(d0 + ty + i) * S_ + s0 + tx];
        __syncthreads();
        bf16* xbp = xb + ((size_t)b * S_ + s0) * D_ + d0;
#pragma unroll
        for (int i = 0; i < 32; i += 8)
            xbp[(size_t)(ty + i) * D_ + tx] = (bf16)tile[tx][ty + i];
    } else {                                     // weight-pack part: 256 blocks
        const int f0 = ((bid - 4096) * 256 + threadIdx.x) * 16;  // 0..1048560
        const int src = f0 >> 18;                // 262144 elems per matrix
        const int off = f0 & 262143;
        const float* W = (src == 0) ? Wq : (src == 1) ? Wk : (src == 2) ? Wv : W0;
        float4 v0 = *(const float4*)&W[off];
        float4 v1 = *(const float4*)&W[off + 4];
        float4 v2 = *(const float4*)&W[off + 8];
        float4 v3 = *(const float4*)&W[off + 12];
        bf16x8 h0 = {(bf16)v0.x, (bf16)v0.y, (bf16)v0.z, (bf16)v0.w,
                     (bf16)v1.x, (bf16)v1.y, (bf16)v1.z, (bf16)v1.w};
        bf16x8 h1 = {(bf16)v2.x, (bf16)v2.y, (bf16)v2.z, (bf16)v2.w,
                     (bf16)v3.x, (bf16)v3.y, (bf16)v3.z, (bf16)v3.w};
        *(bf16x8*)&Wb[f0]     = h0;
        *(bf16x8*)&Wb[f0 + 8] = h1;
    }
}

// ---------------------------------------------------------------------------
// Kernel 2: fused QKV GEMM, m97-style core.
//  - V stored transposed (B,H,DV,S) AND key-swizzled within 32-groups:
//    original key 16h+4q+r (in group) -> stored position 8q+4h+r, so flash
//    can read its PV A-frag with ONE bf16x8 load.
//  - Q/K epilogue: LDS-transpose (union over staging bufs) -> bf16x8 stores.
// ---------------------------------------------------------------------------
__global__ __launch_bounds__(256) void gemm_qkv(
    const bf16* __restrict__ A, const bf16* __restrict__ Wb,
    const float* __restrict__ bq, const float* __restrict__ bk,
    const float* __restrict__ bv,
    bf16* __restrict__ Q, bf16* __restrict__ K, bf16* __restrict__ Vt) {
    __shared__ union {
        struct { bf16 A[8192]; bf16 B[8192]; } s;
        bf16 T[128][132];                        // epilogue transpose (33792 B)
    } sm;

    const int tid = threadIdx.x;
    const int w = tid >> 6, lane = tid & 63;
    const int m16 = lane & 15, quad = lane >> 4;
    const int wr = w & 1, wc = w >> 1;

    const int nblk = blockIdx.x % 12;            // N = 1536 / 128
    const int mblk = blockIdx.x / 12;            // M = 8192 / 128
    const int m0 = mblk * 128, n0 = nblk * 128;

    f32x4 acc[4][4];
#pragma unroll
    for (int i = 0; i < 4; ++i)
#pragma unroll
        for (int j = 0; j < 4; ++j) acc[i][j] = (f32x4){0.f, 0.f, 0.f, 0.f};

    for (int k0 = 0; k0 < D_; k0 += 64) {
        __syncthreads();
#pragma unroll
        for (int i = 0; i < 4; ++i) {            // wave w stages chunks w*4..w*4+3
            const int c  = w * 4 + i;
            const int mt = c >> 1, kk = c & 1;
            const int row = mt * 16 + m16;
            const int col = k0 + kk * 32 + quad * 8;
            GLOAD_LDS(&A[(size_t)(m0 + row) * D_ + col],  &sm.s.A[(c * 64 + lane) * 8]);
            GLOAD_LDS(&Wb[(size_t)(n0 + row) * D_ + col], &sm.s.B[(c * 64 + lane) * 8]);
        }
        __syncthreads();
#pragma unroll
        for (int kk = 0; kk < 2; ++kk) {
            bf16x8 af[4], bfv[4];
#pragma unroll
            for (int t = 0; t < 4; ++t) {
                af[t]  = *(const bf16x8*)&sm.s.A[(((wr * 4 + t) * 2 + kk) * 64 + lane) * 8];
                bfv[t] = *(const bf16x8*)&sm.s.B[(((wc * 4 + t) * 2 + kk) * 64 + lane) * 8];
            }
#pragma unroll
            for (int mt = 0; mt < 4; ++mt)
#pragma unroll
                for (int nt = 0; nt < 4; ++nt)
                    acc[mt][nt] = MFMA(af[mt], bfv[nt], acc[mt][nt]);
        }
    }

    const int proj = n0 >> 9;                    // 128-tiles never straddle
    const float* bias = (proj == 0) ? bq : (proj == 1) ? bk : bv;

    if (proj == 2) {                             // V: direct swizzled store
#pragma unroll
        for (int mt = 0; mt < 4; ++mt)
#pragma unroll
            for (int nt = 0; nt < 4; ++nt) {
                const int nr = (n0 + wc * 64 + nt * 16 + m16) & 511;
                const int h = nr >> 6, e = nr & 63;
                const float bia = bias[nr];
                const int srow = m0 + wr * 64 + mt * 16 + quad * 4;
                const int b = srow >> 11, s = srow & 2047;
                const int s2 = (s & ~31) | (quad * 8 + (mt & 1) * 4);  // key swizzle
                bf16x4 hv;
#pragma unroll
                for (int r = 0; r < 4; ++r) hv[r] = (bf16)(acc[mt][nt][r] + bia);
                *(bf16x4*)&Vt[(((size_t)b * H_ + h) * DV_ + e) * S_ + s2] = hv;
            }
    } else {                                     // Q/K: LDS transpose -> bf16x8
        __syncthreads();
#pragma unroll
        for (int mt = 0; mt < 4; ++mt)
#pragma unroll
            for (int nt = 0; nt < 4; ++nt) {
                const int nloc = wc * 64 + nt * 16 + m16;
                const float bia = bias[(n0 + nloc) & 511];
#pragma unroll
                for (int r = 0; r < 4; ++r)
                    sm.T[wr * 64 + mt * 16 + quad * 4 + r][nloc] =
                        (bf16)(acc[mt][nt][r] + bia);
            }
        __syncthreads();
        const int rloc = tid >> 1, cb = (tid & 1) * 64;
        const int M = m0 + rloc, b = M >> 11, s = M & 2047;
        const int nrb = (n0 + cb) & 511;
        const int h = nrb >> 6;
        bf16* dst = ((proj == 0) ? Q : K) + (((size_t)b * H_ + h) * S_ + s) * DV_;
#pragma unroll
        for (int u = 0; u < 8; ++u)
            *(bf16x8*)&dst[u * 8] = *(const bf16x8*)&sm.T[rloc][cb + u * 8];
    }
}

// ---------------------------------------------------------------------------
// Kernel 3: flash attention v6 — 32 q-rows/block, key-split waves, zero loop
// LDS, 16B V loads via pre-swizzled Vt. Target 3 waves/SIMD.
// ---------------------------------------------------------------------------
__global__ __launch_bounds__(256, 3) void flash_attn(
    const bf16* __restrict__ Q, const bf16* __restrict__ K, const bf16* __restrict__ Vt,
    const float* __restrict__ mask, bf16* __restrict__ heads) {
    __shared__ struct { float O[64][33]; float L[32]; } red;

    const int bidx = blockIdx.x;                 // B*H*(S/32) = 2048
    const int qblk = bidx & 63;
    const int h    = (bidx >> 6) & 7;
    const int b    = bidx >> 9;
    const int q0   = qblk * 32;

    const int tid = threadIdx.x;
    const int w = tid >> 6, lane = tid & 63;
    const int m16 = lane & 15, quad = lane >> 4;

    const bf16* Qp = Q  + ((size_t)b * H_ + h) * S_ * DV_;
    const bf16* Kp = K  + ((size_t)b * H_ + h) * S_ * DV_;
    const bf16* Vp = Vt + ((size_t)b * H_ + h) * DV_ * S_;
    const float* mp = mask + (size_t)b * S_;

    // Q B-frags for 32 q-rows, pre-scaled by 1/sqrt(64) (exact in bf16)
    bf16x8 qf[2][2];
#pragma unroll
    for (int qt = 0; qt < 2; ++qt)
#pragma unroll
        for (int kk = 0; kk < 2; ++kk) {
            bf16x8 v = *(const bf16x8*)&Qp[(size_t)(q0 + qt * 16 + m16) * DV_ +
                                           kk * 32 + quad * 8];
#pragma unroll
            for (int i = 0; i < 8; ++i) v[i] = (bf16)((float)v[i] * 0.125f);
            qf[qt][kk] = v;
        }

    bf16x8 ones;
#pragma unroll
    for (int i = 0; i < 8; ++i) ones[i] = (bf16)1.0f;

    f32x4 o[4][2];                               // O^T[e=16mt+4quad+r][q=16qt+m16]
    f32x4 lacc[2];
#pragma unroll
    for (int mt = 0; mt < 4; ++mt)
#pragma unroll
        for (int qt = 0; qt < 2; ++qt) o[mt][qt] = (f32x4){0.f, 0.f, 0.f, 0.f};
#pragma unroll
    for (int qt = 0; qt < 2; ++qt) lacc[qt] = (f32x4){0.f, 0.f, 0.f, 0.f};

    for (int t0 = 0; t0 < S_; t0 += 128) {
        const int tw = t0 + w * 32;              // this wave's 32 keys

        // K A-frags; V A-frags (single 16B load each — Vt pre-swizzled); mask
        bf16x8 kf[2][2];
#pragma unroll
        for (int tt = 0; tt < 2; ++tt)
#pragma unroll
            for (int kk = 0; kk < 2; ++kk)
                kf[tt][kk] = *(const bf16x8*)&Kp[(size_t)(tw + tt * 16 + m16) * DV_ +
                                                 kk * 32 + quad * 8];
        bf16x8 vf[4];
#pragma unroll
        for (int mt = 0; mt < 4; ++mt)
            vf[mt] = *(const bf16x8*)&Vp[(size_t)(mt * 16 + m16) * S_ + tw + quad * 8];
        const f32x4 mq0 = *(const f32x4*)&mp[tw + quad * 4];
        const f32x4 mq1 = *(const f32x4*)&mp[tw + 16 + quad * 4];

        // S^T tiles: sc[tt][qt], lane = p[t=16tt+4quad+r][q=16qt+m16]
        f32x4 sc[2][2];
#pragma unroll
        for (int tt = 0; tt < 2; ++tt)
#pragma unroll
            for (int qt = 0; qt < 2; ++qt) sc[tt][qt] = (f32x4){0.f, 0.f, 0.f, 0.f};
#pragma unroll
        for (int kk = 0; kk < 2; ++kk)
#pragma unroll
            for (int tt = 0; tt < 2; ++tt)
#pragma unroll
                for (int qt = 0; qt < 2; ++qt)
                    sc[tt][qt] = MFMA(kf[tt][kk], qf[qt][kk], sc[tt][qt]);

        // mask + exp, directly into PV B-frags (in-lane, no LDS)
        f32x4 ng0, ng1;
#pragma unroll
        for (int r = 0; r < 4; ++r) {
            ng0[r] = (1.0f - mq0[r]) * -1e30f;
            ng1[r] = (1.0f - mq1[r]) * -1e30f;
        }
        bf16x8 pf[2];
#pragma unroll
        for (int qt = 0; qt < 2; ++qt)
#pragma unroll
            for (int r = 0; r < 4; ++r) {
                pf[qt][r]     = (bf16)__expf(sc[0][qt][r] * mq0[r] + ng0[r]);
                pf[qt][4 + r] = (bf16)__expf(sc[1][qt][r] * mq1[r] + ng1[r]);
            }

        // PV + l
#pragma unroll
        for (int mt = 0; mt < 4; ++mt)
#pragma unroll
            for (int qt = 0; qt < 2; ++qt) o[mt][qt] = MFMA(vf[mt], pf[qt], o[mt][qt]);
#pragma unroll
        for (int qt = 0; qt < 2; ++qt) lacc[qt] = MFMA(ones, pf[qt], lacc[qt]);
    }

    // ---- cross-wave reduction (turn-based accumulate into red) ----
    __syncthreads();
#pragma unroll
    for (int ww = 0; ww < 4; ++ww) {
        if (w == ww) {
#pragma unroll
            for (int mt = 0; mt < 4; ++mt)
#pragma unroll
                for (int qt = 0; qt < 2; ++qt)
#pragma unroll
                    for (int r = 0; r < 4; ++r) {
                        float* slot = &red.O[mt * 16 + quad * 4 + r][qt * 16 + m16];
                        *slot = (ww == 0) ? o[mt][qt][r] : (*slot + o[mt][qt][r]);
                    }
            if (quad == 0)
#pragma unroll
                for (int qt = 0; qt < 2; ++qt) {
                    float* ls = &red.L[qt * 16 + m16];
                    *ls = (ww == 0) ? lacc[qt][0] : (*ls + lacc[qt][0]);
                }
        }
        __syncthreads();
    }

    // ---- final store: thread -> (q = tid>>3, 8-wide e-chunk = (tid&7)*8) ----
    const int ql = tid >> 3, ec = (tid & 7) * 8;
    const float l  = red.L[ql];
    const float qm = mp[q0 + ql];
    const float inv = qm / l;
    bf16x8 hv;
#pragma unroll
    for (int i = 0; i < 8; ++i) hv[i] = (bf16)(red.O[ec + i][ql] * inv);
    *(bf16x8*)&heads[((size_t)b * S_ + q0 + ql) * D_ + h * DV_ + ec] = hv;
}

// ---------------------------------------------------------------------------
// Kernel 4: out projection (unchanged this round)
// ---------------------------------------------------------------------------
__global__ __launch_bounds__(256) void gemm_out(
    const bf16* __restrict__ A, const bf16* __restrict__ Wb,
    const float* __restrict__ b0, float* __restrict__ outp) {
    __shared__ bf16 Asl[8192];
    __shared__ bf16 Bsl[8192];

    const int tid = threadIdx.x;
    const int w = tid >> 6, lane = tid & 63;
    const int m16 = lane & 15, quad = lane >> 4;
    const int wr = w & 1, wc = w >> 1;

    const int nblk = blockIdx.x & 3;             // N = 512 / 128
    const int mblk = blockIdx.x >> 2;            // M = 8192 / 128
    const int m0 = mblk * 128, n0 = nblk * 128;

    f32x4 acc[4][4];
#pragma unroll
    for (int i = 0; i < 4; ++i)
#pragma unroll
        for (int j = 0; j < 4; ++j) acc[i][j] = (f32x4){0.f, 0.f, 0.f, 0.f};

    for (int k0 = 0; k0 < D_; k0 += 64) {
        __syncthreads();
#pragma unroll
        for (int i = 0; i < 4; ++i) {
            const int c  = w * 4 + i;
            const int mt = c >> 1, kk = c & 1;
            const int row = mt * 16 + m16;
            const int col = k0 + kk * 32 + quad * 8;
            GLOAD_LDS(&A[(size_t)(m0 + row) * D_ + col], &Asl[(c * 64 + lane) * 8]);
            GLOAD_LDS(&Wb[(size_t)(1536 + n0 + row) * D_ + col], &Bsl[(c * 64 + lane) * 8]);
        }
        __syncthreads();
#pragma unroll
        for (int kk = 0; kk < 2; ++kk) {
            bf16x8 af[4], bfv[4];
#pragma unroll
            for (int t = 0; t < 4; ++t) {
                af[t]  = *(const bf16x8*)&Asl[(((wr * 4 + t) * 2 + kk) * 64 + lane) * 8];
                bfv[t] = *(const bf16x8*)&Bsl[(((wc * 4 + t) * 2 + kk) * 64 + lane) * 8];
            }
#pragma unroll
            for (int mt = 0; mt < 4; ++mt)
#pragma unroll
                for (int nt = 0; nt < 4; ++nt)
                    acc[mt][nt] = MFMA(af[mt], bfv[nt], acc[mt][nt]);
        }
    }

#pragma unroll
    for (int mt = 0; mt < 4; ++mt)
#pragma unroll
        for (int nt = 0; nt < 4; ++nt) {
            const int n = n0 + wc * 64 + nt * 16 + m16;
            const float bia = b0[n];
            const int srow = m0 + wr * 64 + mt * 16 + quad * 4;
            const int b = srow >> 11, s = srow & 2047;
            float4 vv;
            vv.x = acc[mt][nt][0] + bia;
            vv.y = acc[mt][nt][1] + bia;
            vv.z = acc[mt][nt][2] + bia;
            vv.w = acc[mt][nt][3] + bia;
            *(float4*)&outp[((size_t)b * D_ + n) * S_ + s] = vv;
        }
}

// ---------------------------------------------------------------------------
extern "C" void kernel_launch(void* const* d_in, const int* in_sizes, int n_in,
                              void* d_out, int out_size, void* d_ws, size_t ws_size,
                              hipStream_t stream) {
    const float* x    = (const float*)d_in[0];
    const float* mask = (const float*)d_in[1];
    const float* Wq   = (const float*)d_in[2];
    const float* bq   = (const float*)d_in[3];
    const float* Wk   = (const float*)d_in[4];
    const float* bk   = (const float*)d_in[5];
    const float* Wv   = (const float*)d_in[6];
    const float* bv   = (const float*)d_in[7];
    const float* W0   = (const float*)d_in[8];
    const float* b0   = (const float*)d_in[9];
    float* out = (float*)d_out;

    char* ws = (char*)d_ws;
    const size_t SEG = (size_t)B_ * S_ * D_ * sizeof(bf16);   // 8 MiB
    bf16* xb    = (bf16*)(ws);            // reused as `heads` after gemm_qkv
    bf16* Qb    = (bf16*)(ws + SEG);
    bf16* Kb    = (bf16*)(ws + 2 * SEG);
    bf16* Vt    = (bf16*)(ws + 3 * SEG);
    bf16* Wb    = (bf16*)(ws + 4 * SEG);  // 2048x512 bf16 = 2 MiB
    bf16* heads = xb;

    prep<<<dim3(4096 + 256), dim3(256), 0, stream>>>(x, Wq, Wk, Wv, W0, xb, Wb);
    gemm_qkv<<<dim3(64 * 12), dim3(256), 0, stream>>>(xb, Wb, bq, bk, bv, Qb, Kb, Vt);
    flash_attn<<<dim3(B_ * H_ * (S_ / 32)), dim3(256), 0, stream>>>(Qb, Kb, Vt, mask, heads);
    gemm_out<<<dim3(64 * 4), dim3(256), 0, stream>>>(heads, Wb, b0, out);
}

// Round 7
// 203.532 us; speedup vs baseline: 1.3311x; 1.3311x over previous
//
#include <hip/hip_runtime.h>

#define B_  4
#define D_  512
#define H_  8
#define DV_ 64
#define S_  2048

typedef __bf16 bf16;
typedef bf16  bf16x8 __attribute__((ext_vector_type(8)));
typedef bf16  bf16x4 __attribute__((ext_vector_type(4)));
typedef float f32x4  __attribute__((ext_vector_type(4)));

#define MFMA(a, b, c) __builtin_amdgcn_mfma_f32_16x16x32_bf16((a), (b), (c), 0, 0, 0)

// async global->LDS, 16B per lane; LDS dest is wave-uniform base + lane*16
#define GLOAD_LDS(g, l)                                                     \
    __builtin_amdgcn_global_load_lds(                                       \
        (const __attribute__((address_space(1))) void*)(g),                 \
        (__attribute__((address_space(3))) void*)(l), 16, 0, 0)

// s_waitcnt with vmcnt(n), lgkm/exp unconstrained (gfx9 encoding)
#define WAIT_VMCNT(n)                                                       \
    __builtin_amdgcn_s_waitcnt(((n) & 15) | (((n) >> 4) << 14) | (7 << 4) | (15 << 8))

// ---------------------------------------------------------------------------
// Kernel 1: prep = transpose x (B,D,S fp32 -> B,S,D bf16)  +  pack weights
// ---------------------------------------------------------------------------
__global__ __launch_bounds__(256) void prep(
    const float* __restrict__ x, const float* __restrict__ Wq,
    const float* __restrict__ Wk, const float* __restrict__ Wv,
    const float* __restrict__ W0, bf16* __restrict__ xb, bf16* __restrict__ Wb) {
    const int bid = blockIdx.x;
    if (bid < 4096) {                            // transpose part
        __shared__ float tile[32][33];
        const int sblk = bid % 64;               // S/32
        const int dblk = (bid / 64) % 16;        // D/32
        const int b    = bid / 1024;
        const int d0 = dblk * 32, s0 = sblk * 32;
        const int tx = threadIdx.x & 31;
        const int ty = threadIdx.x >> 5;         // 0..7
        const float* xp = x + (size_t)b * D_ * S_;
#pragma unroll
        for (int i = 0; i < 32; i += 8)
            tile[ty + i][tx] = xp[(size_t)(d0 + ty + i) * S_ + s0 + tx];
        __syncthreads();
        bf16* xbp = xb + ((size_t)b * S_ + s0) * D_ + d0;
#pragma unroll
        for (int i = 0; i < 32; i += 8)
            xbp[(size_t)(ty + i) * D_ + tx] = (bf16)tile[tx][ty + i];
    } else {                                     // weight-pack part: 256 blocks
        const int f0 = ((bid - 4096) * 256 + threadIdx.x) * 16;  // 0..1048560
        const int src = f0 >> 18;                // 262144 elems per matrix
        const int off = f0 & 262143;
        const float* W = (src == 0) ? Wq : (src == 1) ? Wk : (src == 2) ? Wv : W0;
        float4 v0 = *(const float4*)&W[off];
        float4 v1 = *(const float4*)&W[off + 4];
        float4 v2 = *(const float4*)&W[off + 8];
        float4 v3 = *(const float4*)&W[off + 12];
        bf16x8 h0 = {(bf16)v0.x, (bf16)v0.y, (bf16)v0.z, (bf16)v0.w,
                     (bf16)v1.x, (bf16)v1.y, (bf16)v1.z, (bf16)v1.w};
        bf16x8 h1 = {(bf16)v2.x, (bf16)v2.y, (bf16)v2.z, (bf16)v2.w,
                     (bf16)v3.x, (bf16)v3.y, (bf16)v3.z, (bf16)v3.w};
        *(bf16x8*)&Wb[f0]     = h0;
        *(bf16x8*)&Wb[f0 + 8] = h1;
    }
}

// ---------------------------------------------------------------------------
// Kernel 2: fused QKV GEMM, m97-style core (unchanged from r6; V stored
// transposed + key-swizzled so flash PV A-frags are single 16B chunks).
// ---------------------------------------------------------------------------
__global__ __launch_bounds__(256) void gemm_qkv(
    const bf16* __restrict__ A, const bf16* __restrict__ Wb,
    const float* __restrict__ bq, const float* __restrict__ bk,
    const float* __restrict__ bv,
    bf16* __restrict__ Q, bf16* __restrict__ K, bf16* __restrict__ Vt) {
    __shared__ union {
        struct { bf16 A[8192]; bf16 B[8192]; } s;
        bf16 T[128][132];                        // epilogue transpose (33792 B)
    } sm;

    const int tid = threadIdx.x;
    const int w = tid >> 6, lane = tid & 63;
    const int m16 = lane & 15, quad = lane >> 4;
    const int wr = w & 1, wc = w >> 1;

    const int nblk = blockIdx.x % 12;            // N = 1536 / 128
    const int mblk = blockIdx.x / 12;            // M = 8192 / 128
    const int m0 = mblk * 128, n0 = nblk * 128;

    f32x4 acc[4][4];
#pragma unroll
    for (int i = 0; i < 4; ++i)
#pragma unroll
        for (int j = 0; j < 4; ++j) acc[i][j] = (f32x4){0.f, 0.f, 0.f, 0.f};

    for (int k0 = 0; k0 < D_; k0 += 64) {
        __syncthreads();
#pragma unroll
        for (int i = 0; i < 4; ++i) {            // wave w stages chunks w*4..w*4+3
            const int c  = w * 4 + i;
            const int mt = c >> 1, kk = c & 1;
            const int row = mt * 16 + m16;
            const int col = k0 + kk * 32 + quad * 8;
            GLOAD_LDS(&A[(size_t)(m0 + row) * D_ + col],  &sm.s.A[(c * 64 + lane) * 8]);
            GLOAD_LDS(&Wb[(size_t)(n0 + row) * D_ + col], &sm.s.B[(c * 64 + lane) * 8]);
        }
        __syncthreads();
#pragma unroll
        for (int kk = 0; kk < 2; ++kk) {
            bf16x8 af[4], bfv[4];
#pragma unroll
            for (int t = 0; t < 4; ++t) {
                af[t]  = *(const bf16x8*)&sm.s.A[(((wr * 4 + t) * 2 + kk) * 64 + lane) * 8];
                bfv[t] = *(const bf16x8*)&sm.s.B[(((wc * 4 + t) * 2 + kk) * 64 + lane) * 8];
            }
#pragma unroll
            for (int mt = 0; mt < 4; ++mt)
#pragma unroll
                for (int nt = 0; nt < 4; ++nt)
                    acc[mt][nt] = MFMA(af[mt], bfv[nt], acc[mt][nt]);
        }
    }

    const int proj = n0 >> 9;                    // 128-tiles never straddle
    const float* bias = (proj == 0) ? bq : (proj == 1) ? bk : bv;

    if (proj == 2) {                             // V: direct swizzled store
#pragma unroll
        for (int mt = 0; mt < 4; ++mt)
#pragma unroll
            for (int nt = 0; nt < 4; ++nt) {
                const int nr = (n0 + wc * 64 + nt * 16 + m16) & 511;
                const int h = nr >> 6, e = nr & 63;
                const float bia = bias[nr];
                const int srow = m0 + wr * 64 + mt * 16 + quad * 4;
                const int b = srow >> 11, s = srow & 2047;
                const int s2 = (s & ~31) | (quad * 8 + (mt & 1) * 4);  // key swizzle
                bf16x4 hv;
#pragma unroll
                for (int r = 0; r < 4; ++r) hv[r] = (bf16)(acc[mt][nt][r] + bia);
                *(bf16x4*)&Vt[(((size_t)b * H_ + h) * DV_ + e) * S_ + s2] = hv;
            }
    } else {                                     // Q/K: LDS transpose -> bf16x8
        __syncthreads();
#pragma unroll
        for (int mt = 0; mt < 4; ++mt)
#pragma unroll
            for (int nt = 0; nt < 4; ++nt) {
                const int nloc = wc * 64 + nt * 16 + m16;
                const float bia = bias[(n0 + nloc) & 511];
#pragma unroll
                for (int r = 0; r < 4; ++r)
                    sm.T[wr * 64 + mt * 16 + quad * 4 + r][nloc] =
                        (bf16)(acc[mt][nt][r] + bia);
            }
        __syncthreads();
        const int rloc = tid >> 1, cb = (tid & 1) * 64;
        const int M = m0 + rloc, b = M >> 11, s = M & 2047;
        const int nrb = (n0 + cb) & 511;
        const int h = nrb >> 6;
        bf16* dst = ((proj == 0) ? Q : K) + (((size_t)b * H_ + h) * S_ + s) * DV_;
#pragma unroll
        for (int u = 0; u < 8; ++u)
            *(bf16x8*)&dst[u * 8] = *(const bf16x8*)&sm.T[rloc][cb + u * 8];
    }
}

// ---------------------------------------------------------------------------
// Kernel 3: flash attention v7 — BM=64, key-split waves, wave-private
// double-buffered global_load_lds staging, ZERO barriers in the K-loop.
//  - XOR-swizzled LDS chunk placement: slot(row,cc) = row*8 + (cc ^ (row&7))
//    for K (32x64), slot(e,kc) = e*4 + (kc ^ (e&3)) for V (64x32) ->
//    lane-linear GLOAD writes AND 2-way-free ds_read_b128 frag reads.
//  - Pipeline: issue iter i+1's 8 GLOADs, s_waitcnt vmcnt(8) -> iter i's
//    batch complete. Mask pre-staged to LDS (keeps vmcnt FIFO clean).
//  - S^T trick + in-register P (verified r5/r6); l via ones-MFMA.
// ---------------------------------------------------------------------------
__global__ __launch_bounds__(256, 2) void flash_attn(
    const bf16* __restrict__ Q, const bf16* __restrict__ K, const bf16* __restrict__ Vt,
    const float* __restrict__ mask, bf16* __restrict__ heads) {
    __shared__ union {
        struct {
            bf16 Kl[2][4][2048];                 // [buf][wave][32 keys x 64 d]
            bf16 Vl[2][4][2048];                 // [buf][wave][64 e x 32 keys]
            float Ms[2048];
        } s;
        struct { float O[64][65]; float L[64]; } red;
    } sm;

    const int bidx = blockIdx.x;                 // B*H*(S/64) = 1024
    const int qblk = bidx & 31;
    const int h    = (bidx >> 5) & 7;
    const int b    = bidx >> 8;
    const int q0   = qblk * 64;

    const int tid = threadIdx.x;
    const int w = tid >> 6, lane = tid & 63;
    const int m16 = lane & 15, quad = lane >> 4;

    const bf16* Qp = Q  + ((size_t)b * H_ + h) * S_ * DV_;
    const bf16* Kp = K  + ((size_t)b * H_ + h) * S_ * DV_;
    const bf16* Vp = Vt + ((size_t)b * H_ + h) * DV_ * S_;
    const float* mp = mask + (size_t)b * S_;

    // per-lane staging constants (p-independent; see swizzle algebra)
    const int krow = lane >> 3;                          // 0..7
    const int kcol = ((lane & 7) ^ krow) * 8;            // elem offset in K row
    const int vrow = lane >> 2;                          // 0..15
    const int vcol = ((lane & 3) ^ (vrow & 3)) * 8;      // elem offset in V row

    // Q B-frags for 64 q-rows, pre-scaled by 1/sqrt(64) (exact in bf16)
    bf16x8 qf[4][2];
#pragma unroll
    for (int qt = 0; qt < 4; ++qt)
#pragma unroll
        for (int kk = 0; kk < 2; ++kk) {
            bf16x8 v = *(const bf16x8*)&Qp[(size_t)(q0 + qt * 16 + m16) * DV_ +
                                           kk * 32 + quad * 8];
#pragma unroll
            for (int i = 0; i < 8; ++i) v[i] = (bf16)((float)v[i] * 0.125f);
            qf[qt][kk] = v;
        }

    bf16x8 ones;
#pragma unroll
    for (int i = 0; i < 8; ++i) ones[i] = (bf16)1.0f;

    f32x4 o[4][4];                               // O^T[e=16mt+4quad+r][q=16qt+m16]
    f32x4 lacc[4];
#pragma unroll
    for (int mt = 0; mt < 4; ++mt)
#pragma unroll
        for (int qt = 0; qt < 4; ++qt) o[mt][qt] = (f32x4){0.f, 0.f, 0.f, 0.f};
#pragma unroll
    for (int qt = 0; qt < 4; ++qt) lacc[qt] = (f32x4){0.f, 0.f, 0.f, 0.f};

    // ---- prologue: stage mask (all S) + batch 0 (buf 0), one barrier ----
#pragma unroll
    for (int p = 0; p < 2; ++p)
        GLOAD_LDS(&mp[(p * 256 + tid) * 4], &sm.s.Ms[(p * 256 + tid) * 4]);
    {
        const int tw = w * 32;
#pragma unroll
        for (int p = 0; p < 4; ++p)
            GLOAD_LDS(&Kp[(size_t)(tw + p * 8 + krow) * DV_ + kcol],
                      &sm.s.Kl[0][w][(p * 64 + lane) * 8]);
#pragma unroll
        for (int p = 0; p < 4; ++p)
            GLOAD_LDS(&Vp[(size_t)(p * 16 + vrow) * S_ + tw + vcol],
                      &sm.s.Vl[0][w][(p * 64 + lane) * 8]);
    }
    __syncthreads();                             // mask visible; batch0 done

    for (int i = 0; i < 16; ++i) {
        const int tw = i * 128 + w * 32;         // this wave's 32 keys
        if (i < 15) {                            // issue batch i+1 -> buf (i+1)&1
            const int twn = tw + 128;
            const int nb = (i + 1) & 1;
#pragma unroll
            for (int p = 0; p < 4; ++p)
                GLOAD_LDS(&Kp[(size_t)(twn + p * 8 + krow) * DV_ + kcol],
                          &sm.s.Kl[nb][w][(p * 64 + lane) * 8]);
#pragma unroll
            for (int p = 0; p < 4; ++p)
                GLOAD_LDS(&Vp[(size_t)(p * 16 + vrow) * S_ + twn + vcol],
                          &sm.s.Vl[nb][w][(p * 64 + lane) * 8]);
            WAIT_VMCNT(8);                       // batch i complete
        } else {
            WAIT_VMCNT(0);
        }
        const int buf = i & 1;

        // K A-frags from LDS (swizzle-inverted: retrieves chunk kk*4+quad)
        bf16x8 kf[2][2];
#pragma unroll
        for (int tt = 0; tt < 2; ++tt)
#pragma unroll
            for (int kk = 0; kk < 2; ++kk)
                kf[tt][kk] = *(const bf16x8*)&sm.s.Kl[buf][w][
                    ((tt * 16 + m16) * 8 + ((kk * 4 + quad) ^ (m16 & 7))) * 8];
        // V A-frags from LDS (retrieves chunk quad)
        bf16x8 vf[4];
#pragma unroll
        for (int mt = 0; mt < 4; ++mt)
            vf[mt] = *(const bf16x8*)&sm.s.Vl[buf][w][
                ((mt * 16 + m16) * 4 + (quad ^ (m16 & 3))) * 8];
        const f32x4 mq0 = *(const f32x4*)&sm.s.Ms[tw + quad * 4];
        const f32x4 mq1 = *(const f32x4*)&sm.s.Ms[tw + 16 + quad * 4];

        // S^T tiles: sc[tt][qt], lane = p[t=16tt+4quad+r][q=16qt+m16]
        f32x4 sc[2][4];
#pragma unroll
        for (int tt = 0; tt < 2; ++tt)
#pragma unroll
            for (int qt = 0; qt < 4; ++qt) sc[tt][qt] = (f32x4){0.f, 0.f, 0.f, 0.f};
#pragma unroll
        for (int kk = 0; kk < 2; ++kk)
#pragma unroll
            for (int tt = 0; tt < 2; ++tt)
#pragma unroll
                for (int qt = 0; qt < 4; ++qt)
                    sc[tt][qt] = MFMA(kf[tt][kk], qf[qt][kk], sc[tt][qt]);

        // mask + exp, directly into PV B-frags (in-lane, no LDS)
        f32x4 ng0, ng1;
#pragma unroll
        for (int r = 0; r < 4; ++r) {
            ng0[r] = (1.0f - mq0[r]) * -1e30f;
            ng1[r] = (1.0f - mq1[r]) * -1e30f;
        }
        bf16x8 pf[4];
#pragma unroll
        for (int qt = 0; qt < 4; ++qt)
#pragma unroll
            for (int r = 0; r < 4; ++r) {
                pf[qt][r]     = (bf16)__expf(sc[0][qt][r] * mq0[r] + ng0[r]);
                pf[qt][4 + r] = (bf16)__expf(sc[1][qt][r] * mq1[r] + ng1[r]);
            }

        // PV + l
#pragma unroll
        for (int mt = 0; mt < 4; ++mt)
#pragma unroll
            for (int qt = 0; qt < 4; ++qt) o[mt][qt] = MFMA(vf[mt], pf[qt], o[mt][qt]);
#pragma unroll
        for (int qt = 0; qt < 4; ++qt) lacc[qt] = MFMA(ones, pf[qt], lacc[qt]);
    }

    // ---- cross-wave reduction (turn-based accumulate into red) ----
    __syncthreads();
#pragma unroll
    for (int ww = 0; ww < 4; ++ww) {
        if (w == ww) {
#pragma unroll
            for (int mt = 0; mt < 4; ++mt)
#pragma unroll
                for (int qt = 0; qt < 4; ++qt)
#pragma unroll
                    for (int r = 0; r < 4; ++r) {
                        float* slot = &sm.red.O[mt * 16 + quad * 4 + r][qt * 16 + m16];
                        *slot = (ww == 0) ? o[mt][qt][r] : (*slot + o[mt][qt][r]);
                    }
            if (quad == 0)
#pragma unroll
                for (int qt = 0; qt < 4; ++qt) {
                    float* ls = &sm.red.L[qt * 16 + m16];
                    *ls = (ww == 0) ? lacc[qt][0] : (*ls + lacc[qt][0]);
                }
        }
        __syncthreads();
    }

    // ---- final store: thread -> (q = tid>>2, 16-wide e-chunk = (tid&3)*16) ----
    const int ql = tid >> 2, ec = (tid & 3) * 16;
    const float l  = sm.red.L[ql];
    const float qm = mp[q0 + ql];
    const float inv = qm / l;
    bf16x8 hv[2];
#pragma unroll
    for (int c = 0; c < 2; ++c)
#pragma unroll
        for (int i = 0; i < 8; ++i)
            hv[c][i] = (bf16)(sm.red.O[ec + c * 8 + i][ql] * inv);
    bf16* dst = &heads[((size_t)b * S_ + q0 + ql) * D_ + h * DV_ + ec];
    *(bf16x8*)(dst)     = hv[0];
    *(bf16x8*)(dst + 8) = hv[1];
}

// ---------------------------------------------------------------------------
// Kernel 4: out projection (unchanged this round)
// ---------------------------------------------------------------------------
__global__ __launch_bounds__(256) void gemm_out(
    const bf16* __restrict__ A, const bf16* __restrict__ Wb,
    const float* __restrict__ b0, float* __restrict__ outp) {
    __shared__ bf16 Asl[8192];
    __shared__ bf16 Bsl[8192];

    const int tid = threadIdx.x;
    const int w = tid >> 6, lane = tid & 63;
    const int m16 = lane & 15, quad = lane >> 4;
    const int wr = w & 1, wc = w >> 1;

    const int nblk = blockIdx.x & 3;             // N = 512 / 128
    const int mblk = blockIdx.x >> 2;            // M = 8192 / 128
    const int m0 = mblk * 128, n0 = nblk * 128;

    f32x4 acc[4][4];
#pragma unroll
    for (int i = 0; i < 4; ++i)
#pragma unroll
        for (int j = 0; j < 4; ++j) acc[i][j] = (f32x4){0.f, 0.f, 0.f, 0.f};

    for (int k0 = 0; k0 < D_; k0 += 64) {
        __syncthreads();
#pragma unroll
        for (int i = 0; i < 4; ++i) {
            const int c  = w * 4 + i;
            const int mt = c >> 1, kk = c & 1;
            const int row = mt * 16 + m16;
            const int col = k0 + kk * 32 + quad * 8;
            GLOAD_LDS(&A[(size_t)(m0 + row) * D_ + col], &Asl[(c * 64 + lane) * 8]);
            GLOAD_LDS(&Wb[(size_t)(1536 + n0 + row) * D_ + col], &Bsl[(c * 64 + lane) * 8]);
        }
        __syncthreads();
#pragma unroll
        for (int kk = 0; kk < 2; ++kk) {
            bf16x8 af[4], bfv[4];
#pragma unroll
            for (int t = 0; t < 4; ++t) {
                af[t]  = *(const bf16x8*)&Asl[(((wr * 4 + t) * 2 + kk) * 64 + lane) * 8];
                bfv[t] = *(const bf16x8*)&Bsl[(((wc * 4 + t) * 2 + kk) * 64 + lane) * 8];
            }
#pragma unroll
            for (int mt = 0; mt < 4; ++mt)
#pragma unroll
                for (int nt = 0; nt < 4; ++nt)
                    acc[mt][nt] = MFMA(af[mt], bfv[nt], acc[mt][nt]);
        }
    }

#pragma unroll
    for (int mt = 0; mt < 4; ++mt)
#pragma unroll
        for (int nt = 0; nt < 4; ++nt) {
            const int n = n0 + wc * 64 + nt * 16 + m16;
            const float bia = b0[n];
            const int srow = m0 + wr * 64 + mt * 16 + quad * 4;
            const int b = srow >> 11, s = srow & 2047;
            float4 vv;
            vv.x = acc[mt][nt][0] + bia;
            vv.y = acc[mt][nt][1] + bia;
            vv.z = acc[mt][nt][2] + bia;
            vv.w = acc[mt][nt][3] + bia;
            *(float4*)&outp[((size_t)b * D_ + n) * S_ + s] = vv;
        }
}

// ---------------------------------------------------------------------------
extern "C" void kernel_launch(void* const* d_in, const int* in_sizes, int n_in,
                              void* d_out, int out_size, void* d_ws, size_t ws_size,
                              hipStream_t stream) {
    const float* x    = (const float*)d_in[0];
    const float* mask = (const float*)d_in[1];
    const float* Wq   = (const float*)d_in[2];
    const float* bq   = (const float*)d_in[3];
    const float* Wk   = (const float*)d_in[4];
    const float* bk   = (const float*)d_in[5];
    const float* Wv   = (const float*)d_in[6];
    const float* bv   = (const float*)d_in[7];
    const float* W0   = (const float*)d_in[8];
    const float* b0   = (const float*)d_in[9];
    float* out = (float*)d_out;

    char* ws = (char*)d_ws;
    const size_t SEG = (size_t)B_ * S_ * D_ * sizeof(bf16);   // 8 MiB
    bf16* xb    = (bf16*)(ws);            // reused as `heads` after gemm_qkv
    bf16* Qb    = (bf16*)(ws + SEG);
    bf16* Kb    = (bf16*)(ws + 2 * SEG);
    bf16* Vt    = (bf16*)(ws + 3 * SEG);
    bf16* Wb    = (bf16*)(ws + 4 * SEG);  // 2048x512 bf16 = 2 MiB
    bf16* heads = xb;

    prep<<<dim3(4096 + 256), dim3(256), 0, stream>>>(x, Wq, Wk, Wv, W0, xb, Wb);
    gemm_qkv<<<dim3(64 * 12), dim3(256), 0, stream>>>(xb, Wb, bq, bk, bv, Qb, Kb, Vt);
    flash_attn<<<dim3(B_ * H_ * (S_ / 64)), dim3(256), 0, stream>>>(Qb, Kb, Vt, mask, heads);
    gemm_out<<<dim3(64 * 4), dim3(256), 0, stream>>>(heads, Wb, b0, out);
}